// Round 1
// baseline (483.760 us; speedup 1.0000x reference)
//
#include <hip/hip_runtime.h>

typedef __attribute__((ext_vector_type(8))) short bf16x8;
typedef __attribute__((ext_vector_type(4))) float f32x4;
typedef __attribute__((ext_vector_type(4))) unsigned short us4;

#define MFMA16 __builtin_amdgcn_mfma_f32_16x16x32_bf16

__device__ __forceinline__ unsigned short f2bf(float f) {
  union { float f; unsigned u; } v; v.f = f;
  unsigned r = v.u + 0x7FFFu + ((v.u >> 16) & 1u);
  return (unsigned short)(r >> 16);
}

// ---------------- LayerNorm: x fp32 [BHS, 256] -> xn bf16 ----------------
__global__ __launch_bounds__(256) void ln_kernel(const float* __restrict__ x,
    const float* __restrict__ gamma, const float* __restrict__ beta,
    unsigned short* __restrict__ xn)
{
  int row = blockIdx.x * 4 + (threadIdx.x >> 6);
  int lane = threadIdx.x & 63;
  const float* xr = x + (size_t)row * 256;
  f32x4 v = *(const f32x4*)(xr + lane * 4);
  float s  = v[0] + v[1] + v[2] + v[3];
  float s2 = v[0]*v[0] + v[1]*v[1] + v[2]*v[2] + v[3]*v[3];
  #pragma unroll
  for (int off = 1; off < 64; off <<= 1) {
    s  += __shfl_xor(s, off);
    s2 += __shfl_xor(s2, off);
  }
  float mu   = s * (1.0f / 256.0f);
  float var  = s2 * (1.0f / 256.0f) - mu * mu;
  float rstd = rsqrtf(var + 1e-5f);
  f32x4 g  = *(const f32x4*)(gamma + lane * 4);
  f32x4 bb = *(const f32x4*)(beta  + lane * 4);
  us4 o;
  #pragma unroll
  for (int j = 0; j < 4; j++) o[j] = f2bf((v[j] - mu) * rstd * g[j] + bb[j]);
  *(us4*)(xn + (size_t)row * 256 + lane * 4) = o;
}

// ---------------- fp32 -> bf16 cast ----------------
__global__ __launch_bounds__(256) void cvt_kernel(const float* __restrict__ in,
    unsigned short* __restrict__ out, int n4)
{
  int i = blockIdx.x * 256 + threadIdx.x;
  if (i >= n4) return;
  f32x4 v = *(const f32x4*)(in + (size_t)i * 4);
  us4 o;
  #pragma unroll
  for (int j = 0; j < 4; j++) o[j] = f2bf(v[j]);
  *(us4*)(out + (size_t)i * 4) = o;
}

// ---------------- batched GEMM:  C[bh][M][N] = A[bh][M][256] * B[bh&15][N][256]^T  (bf16) ----
__global__ __launch_bounds__(256) void gemm_bt(const unsigned short* __restrict__ Ag,
    const unsigned short* __restrict__ Bg, unsigned short* __restrict__ Cg, int N)
{
  constexpr int K = 256, M = 1024;
  __shared__ unsigned short As[64][72];   // padded: row stride 144B, 2-way-free banks
  __shared__ unsigned short Bs[64][72];
  int bh = blockIdx.z;
  int m0 = blockIdx.x * 64, n0 = blockIdx.y * 64;
  const unsigned short* Ab = Ag + (size_t)bh * M * K + (size_t)m0 * K;
  const unsigned short* Bb = Bg + (size_t)(bh & 15) * N * K + (size_t)n0 * K;
  int tid = threadIdx.x, lane = tid & 63;
  int wave = tid >> 6, wm = wave >> 1, wn = wave & 1;
  int lr = lane & 15, lk = (lane >> 4) * 8;
  f32x4 acc[2][2] = {};
  for (int k0 = 0; k0 < K; k0 += 64) {
    #pragma unroll
    for (int i = 0; i < 2; i++) {
      int c = tid + 256 * i;
      int r = c >> 3, c8 = (c & 7) * 8;
      *(bf16x8*)&As[r][c8] = *(const bf16x8*)(Ab + (size_t)r * K + k0 + c8);
      *(bf16x8*)&Bs[r][c8] = *(const bf16x8*)(Bb + (size_t)r * K + k0 + c8);
    }
    __syncthreads();
    #pragma unroll
    for (int ks = 0; ks < 2; ks++) {
      bf16x8 af[2], bfr[2];
      #pragma unroll
      for (int mf = 0; mf < 2; mf++) af[mf]  = *(const bf16x8*)&As[wm*32 + mf*16 + lr][ks*32 + lk];
      #pragma unroll
      for (int nf = 0; nf < 2; nf++) bfr[nf] = *(const bf16x8*)&Bs[wn*32 + nf*16 + lr][ks*32 + lk];
      #pragma unroll
      for (int mf = 0; mf < 2; mf++)
        #pragma unroll
        for (int nf = 0; nf < 2; nf++)
          acc[mf][nf] = MFMA16(af[mf], bfr[nf], acc[mf][nf], 0, 0, 0);
    }
    __syncthreads();
  }
  unsigned short* Cb = Cg + (size_t)bh * M * N;
  int g = lane >> 4;
  #pragma unroll
  for (int mf = 0; mf < 2; mf++)
    #pragma unroll
    for (int nf = 0; nf < 2; nf++)
      #pragma unroll
      for (int i = 0; i < 4; i++) {
        int row = m0 + wm*32 + mf*16 + g*4 + i;
        int col = n0 + wn*32 + nf*16 + lr;
        Cb[(size_t)row * N + col] = f2bf(acc[mf][nf][i]);
      }
}

// ---------------- fused attention ----------------
// grid: 1024 blocks = 64 (b,h) x 16 q-tiles of 64 rows; 256 threads = 4 waves x 16 rows
__global__ __launch_bounds__(256) void attn_kernel(const unsigned short* __restrict__ Q,
    const unsigned short* __restrict__ Kt, const unsigned short* __restrict__ V,
    float* __restrict__ Out)
{
  constexpr int S = 1024, AD = 128, OD = 256;
  __shared__ unsigned short q_lds[64][136];    // padded (272B rows)
  __shared__ unsigned short k_lds[32][136];
  __shared__ unsigned short vT[256][40];       // V transposed: vT[o][t], padded 80B rows
  __shared__ unsigned short p1_lds[4][16][40]; // per-wave P staging (acc-layout -> A-frag transpose)
  __shared__ unsigned short p2_lds[4][16][40];

  int bid = blockIdx.x;
  int bh = bid >> 4, qt = bid & 15;
  int tid = threadIdx.x, lane = tid & 63, w = tid >> 6;
  int lr = lane & 15, g = lane >> 4, lk = g * 8;
  const unsigned short* Qb = Q  + ((size_t)bh * S + qt * 64) * AD;
  const unsigned short* Kb = Kt + (size_t)bh * S * AD;
  const unsigned short* Vb = V  + (size_t)bh * S * OD;

  // stage q tile 64x128 and hoist per-wave A-fragments (reused across all k-tiles)
  #pragma unroll
  for (int i = 0; i < 4; i++) {
    int c = tid + 256 * i;
    int r = c >> 4, c8 = (c & 15) * 8;
    *(bf16x8*)&q_lds[r][c8] = *(const bf16x8*)(Qb + (size_t)r * AD + c8);
  }
  __syncthreads();
  bf16x8 aq[4];
  #pragma unroll
  for (int ks = 0; ks < 4; ks++) aq[ks] = *(const bf16x8*)&q_lds[w*16 + lr][ks*32 + lk];

  float rmin[4], rmax[4];
  #pragma unroll
  for (int i = 0; i < 4; i++) { rmin[i] = 3.0e38f; rmax[i] = -3.0e38f; }

  // ---- pass 1: row min/max of raw scores (scale cancels in normalization) ----
  for (int kt = 0; kt < 32; kt++) {
    const unsigned short* Kp = Kb + (size_t)kt * 32 * AD;
    #pragma unroll
    for (int i = 0; i < 2; i++) {
      int c = tid + 256 * i;
      int r = c >> 4, c8 = (c & 15) * 8;
      *(bf16x8*)&k_lds[r][c8] = *(const bf16x8*)(Kp + (size_t)r * AD + c8);
    }
    __syncthreads();
    #pragma unroll
    for (int nf = 0; nf < 2; nf++) {
      f32x4 acc = {0.f, 0.f, 0.f, 0.f};
      #pragma unroll
      for (int ks = 0; ks < 4; ks++) {
        bf16x8 bk = *(const bf16x8*)&k_lds[nf*16 + lr][ks*32 + lk];
        acc = MFMA16(aq[ks], bk, acc, 0, 0, 0);
      }
      #pragma unroll
      for (int i = 0; i < 4; i++) {
        rmin[i] = fminf(rmin[i], acc[i]);
        rmax[i] = fmaxf(rmax[i], acc[i]);
      }
    }
    __syncthreads();
  }
  // reduce across the 16 lanes holding the same rows (cols) of each C fragment
  #pragma unroll
  for (int off = 1; off < 16; off <<= 1) {
    #pragma unroll
    for (int i = 0; i < 4; i++) {
      rmin[i] = fminf(rmin[i], __shfl_xor(rmin[i], off));
      rmax[i] = fmaxf(rmax[i], __shfl_xor(rmax[i], off));
    }
  }
  float inv[4];
  #pragma unroll
  for (int i = 0; i < 4; i++) inv[i] = 1.0f / (rmax[i] - rmin[i]);

  // ---- pass 2: recompute scores, accumulate E (softmax numerator), Z, G (sigmoid part) ----
  float z[4] = {0.f, 0.f, 0.f, 0.f};
  f32x4 accE[16], accG[16];
  #pragma unroll
  for (int of = 0; of < 16; of++) {
    accE[of] = (f32x4){0.f, 0.f, 0.f, 0.f};
    accG[of] = (f32x4){0.f, 0.f, 0.f, 0.f};
  }

  for (int kt = 0; kt < 32; kt++) {
    const unsigned short* Kp = Kb + (size_t)kt * 32 * AD;
    #pragma unroll
    for (int i = 0; i < 2; i++) {
      int c = tid + 256 * i;
      int r = c >> 4, c8 = (c & 15) * 8;
      *(bf16x8*)&k_lds[r][c8] = *(const bf16x8*)(Kp + (size_t)r * AD + c8);
    }
    const unsigned short* Vp = Vb + (size_t)kt * 32 * OD;
    {
      int tt = tid & 31, oc = tid >> 5;
      #pragma unroll
      for (int i = 0; i < 4; i++) {
        int o0 = oc * 32 + i * 8;
        bf16x8 vv = *(const bf16x8*)(Vp + (size_t)tt * OD + o0);
        #pragma unroll
        for (int j = 0; j < 8; j++) vT[o0 + j][tt] = (unsigned short)vv[j];
      }
    }
    __syncthreads();
    #pragma unroll
    for (int nf = 0; nf < 2; nf++) {
      f32x4 acc = {0.f, 0.f, 0.f, 0.f};
      #pragma unroll
      for (int ks = 0; ks < 4; ks++) {
        bf16x8 bk = *(const bf16x8*)&k_lds[nf*16 + lr][ks*32 + lk];
        acc = MFMA16(aq[ks], bk, acc, 0, 0, 0);
      }
      #pragma unroll
      for (int i = 0; i < 4; i++) {
        float sn = (acc[i] - rmin[i]) * inv[i];
        float p1 = __expf(sn - 1.0f);                    // exp(s_norm - max), max==1
        float p2 = 1.0f / (1.0f + __expf(5.0f - 10.0f * sn));  // sigmoid(10*s_norm - 5)
        z[i] += p1;
        p1_lds[w][g*4 + i][nf*16 + lr] = f2bf(p1);
        p2_lds[w][g*4 + i][nf*16 + lr] = f2bf(p2);
      }
    }
    // per-wave private buffers: same-wave RAW through LDS, compiler inserts lgkmcnt waits
    bf16x8 pa1 = *(const bf16x8*)&p1_lds[w][lr][lk];
    bf16x8 pa2 = *(const bf16x8*)&p2_lds[w][lr][lk];
    #pragma unroll
    for (int of = 0; of < 16; of++) {
      bf16x8 vbf = *(const bf16x8*)&vT[of*16 + lr][lk];
      accE[of] = MFMA16(pa1, vbf, accE[of], 0, 0, 0);
      accG[of] = MFMA16(pa2, vbf, accG[of], 0, 0, 0);
    }
    __syncthreads();
  }

  #pragma unroll
  for (int off = 1; off < 16; off <<= 1)
    #pragma unroll
    for (int i = 0; i < 4; i++) z[i] += __shfl_xor(z[i], off);

  const float c2 = 0.9933071490757153f;    // sigmoid(5)  (sigmoid_sel: max(s_norm)==1)
  const float c1 = 0.0066928509242848554f; // 1 - sigmoid(5)
  float* Ob = Out + ((size_t)bh * S + qt * 64 + w * 16) * OD;
  #pragma unroll
  for (int of = 0; of < 16; of++) {
    #pragma unroll
    for (int i = 0; i < 4; i++) {
      int row = g*4 + i;
      int col = of*16 + lr;
      Ob[(size_t)row * OD + col] = c1 * accE[of][i] / z[i] + c2 * accG[of][i];
    }
  }
}

extern "C" void kernel_launch(void* const* d_in, const int* in_sizes, int n_in,
                              void* d_out, int out_size, void* d_ws, size_t ws_size,
                              hipStream_t stream) {
  const float* x     = (const float*)d_in[0];
  const float* Wq    = (const float*)d_in[1];
  const float* Wk    = (const float*)d_in[2];
  const float* Wv    = (const float*)d_in[3];
  const float* gamma = (const float*)d_in[4];
  const float* beta  = (const float*)d_in[5];
  float* out = (float*)d_out;

  constexpr int B = 4, H = 16, S = 1024, D = 256, A = 128, O = 256;
  constexpr int BH = B * H;

  char* ws = (char*)d_ws;
  size_t off = 0;
  unsigned short* xn  = (unsigned short*)(ws + off); off += (size_t)BH * S * D * 2; // 33.5MB
  unsigned short* qb  = (unsigned short*)(ws + off); off += (size_t)BH * S * A * 2; // 16.8MB
  unsigned short* kb  = (unsigned short*)(ws + off); off += (size_t)BH * S * A * 2; // 16.8MB
  unsigned short* vb  = (unsigned short*)(ws + off); off += (size_t)BH * S * O * 2; // 33.5MB
  unsigned short* wqb = (unsigned short*)(ws + off); off += (size_t)H * A * D * 2;  // 1MB
  unsigned short* wkb = (unsigned short*)(ws + off); off += (size_t)H * A * D * 2;  // 1MB
  unsigned short* wvb = (unsigned short*)(ws + off); off += (size_t)H * O * D * 2;  // 2MB

  // 1) LayerNorm -> bf16
  ln_kernel<<<BH * S / 4, 256, 0, stream>>>(x, gamma, beta, xn);

  // 2) weights -> bf16
  cvt_kernel<<<(H * A * D / 4 + 255) / 256, 256, 0, stream>>>(Wq, wqb, H * A * D / 4);
  cvt_kernel<<<(H * A * D / 4 + 255) / 256, 256, 0, stream>>>(Wk, wkb, H * A * D / 4);
  cvt_kernel<<<(H * O * D / 4 + 255) / 256, 256, 0, stream>>>(Wv, wvb, H * O * D / 4);

  // 3) projections
  gemm_bt<<<dim3(S / 64, A / 64, BH), 256, 0, stream>>>(xn, wqb, qb, A);
  gemm_bt<<<dim3(S / 64, A / 64, BH), 256, 0, stream>>>(xn, wkb, kb, A);
  gemm_bt<<<dim3(S / 64, O / 64, BH), 256, 0, stream>>>(xn, wvb, vb, O);

  // 4) fused two-pass attention
  attn_kernel<<<BH * (S / 64), 256, 0, stream>>>(qb, kb, vb, out);
}